// Round 1
// baseline (120.623 us; speedup 1.0000x reference)
//
#include <hip/hip_runtime.h>
#include <hip/hip_cooperative_groups.h>
#include <math.h>

#define HH 8
#define LL 512
#define LN_EPS 1e-5f
// 1/(3*sqrt(32))
#define KSCALE 0.058925565098878960f

namespace cg = cooperative_groups;

// Single fused cooperative kernel.
// Grid = 64 blocks x 256 threads: block b -> head h = b>>3, row-chunk c = b&7 (64 rows).
// Phase 1: LayerNorm Q/K rows of this (h, chunk) in-register -> LDS (no global staging).
// Phase 2: per-block partial KV/KK/QQ/Ksum -> unique ws slots (no atomics, no memset).
// grid.sync()
// Phase 3: sum the 8 chunk-partials of head h, finalize rows from LDS-resident Q/K/V.
__global__ __launch_bounds__(256) void fused_kernel(
    const float* __restrict__ q_in, const float* __restrict__ k_in,
    const float* __restrict__ v_in, const float* __restrict__ key_len,
    float* __restrict__ ws, float* __restrict__ out)
{
    __shared__ float Qs[64 * 32];
    __shared__ float Ks[64 * 32];
    __shared__ float Vs[64 * 32];
    // stride-33 padding: row-wise reads T[lane*33+e] hit bank (lane+e)%32 -> conflict-free
    __shared__ float KVs[32 * 33];
    __shared__ float KKs[32 * 33];
    __shared__ float QQs[32 * 33];
    __shared__ float Ksum_s[32];

    const int b  = blockIdx.x;     // 0..63
    const int h  = b >> 3;
    const int c  = b & 7;
    const int r0 = c * 64;
    const int t    = threadIdx.x;
    const int lane = t & 31;       // element index within a row
    const int grp  = t >> 5;       // 0..7

    // Workspace layout (all fully written before read; poison-safe):
    float* KVp   = ws;               // [64][1024]  KV[m][d] partials per block
    float* KKp   = ws + 64 * 1024;   // [64][1024]  KK[d][e]
    float* QQp   = ws + 128 * 1024;  // [64][1024]  QQ[d][e]
    float* Ksump = ws + 192 * 1024;  // [64][32]

    // ---------------- Phase 1: LayerNorm into LDS ----------------
    for (int rr = grp; rr < 64; rr += 8) {
        int row = r0 + rr;                        // l (for Q) == s (for K/V)
        int g = (row * HH + h) * 32 + lane;

        float xq = q_in[g];
        float mq = xq;
        #pragma unroll
        for (int off = 16; off > 0; off >>= 1) mq += __shfl_xor(mq, off, 32);
        mq *= (1.0f / 32.0f);
        float cq = xq - mq;
        float vq = cq * cq;
        #pragma unroll
        for (int off = 16; off > 0; off >>= 1) vq += __shfl_xor(vq, off, 32);
        vq *= (1.0f / 32.0f);
        Qs[rr * 32 + lane] = cq * rsqrtf(vq + LN_EPS);

        float xk = k_in[g];
        float mk = xk;
        #pragma unroll
        for (int off = 16; off > 0; off >>= 1) mk += __shfl_xor(mk, off, 32);
        mk *= (1.0f / 32.0f);
        float ck = xk - mk;
        float vk = ck * ck;
        #pragma unroll
        for (int off = 16; off > 0; off >>= 1) vk += __shfl_xor(vk, off, 32);
        vk *= (1.0f / 32.0f);
        Ks[rr * 32 + lane] = ck * rsqrtf(vk + LN_EPS) * (KSCALE * key_len[row]);

        Vs[rr * 32 + lane] = v_in[g];
    }
    __syncthreads();

    // ---------------- Phase 2: per-block partial reductions ----------------
    float kv[4] = {0, 0, 0, 0};
    float kk[4] = {0, 0, 0, 0};
    float qq[4] = {0, 0, 0, 0};
    #pragma unroll 4
    for (int s = 0; s < 64; ++s) {
        float ke = Ks[s * 32 + lane];
        float ve = Vs[s * 32 + lane];
        float qe = Qs[s * 32 + lane];
        #pragma unroll
        for (int j = 0; j < 4; ++j) {
            int d = grp + j * 8;
            float kd = Ks[s * 32 + d];   // broadcast within 32-lane group
            float qd = Qs[s * 32 + d];
            kv[j] += kd * ve;
            kk[j] += kd * ke;
            qq[j] += qd * qe;
        }
    }
    #pragma unroll
    for (int j = 0; j < 4; ++j) {
        int d = grp + j * 8;
        KVp[b * 1024 + lane * 32 + d] = kv[j];   // KV[m][d], m = lane
        KKp[b * 1024 + d * 32 + lane] = kk[j];   // KK[d][e], e = lane
        QQp[b * 1024 + d * 32 + lane] = qq[j];   // QQ[d][e]
    }
    if (t < 32) {
        float acc = 0.0f;
        for (int s = 0; s < 64; ++s) acc += Ks[s * 32 + t];  // bank t each iter, conflict-free
        Ksump[b * 32 + t] = acc;
    }

    __threadfence();            // device-scope release of partials
    cg::this_grid().sync();

    // ---------------- Phase 3: sum partials, finalize rows ----------------
    for (int i = t; i < 1024; i += 256) {
        float skv = 0.0f, skk = 0.0f, sqq = 0.0f;
        #pragma unroll
        for (int cc = 0; cc < 8; ++cc) {
            int idx = (h * 8 + cc) * 1024 + i;
            skv += KVp[idx];
            skk += KKp[idx];
            sqq += QQp[idx];
        }
        int r = i >> 5, e = i & 31;
        KVs[r * 33 + e] = skv;
        KKs[r * 33 + e] = skk;
        QQs[r * 33 + e] = sqq;
    }
    if (t < 32) {
        float a = 0.0f;
        #pragma unroll
        for (int cc = 0; cc < 8; ++cc) a += Ksump[(h * 8 + cc) * 32 + t];
        Ksum_s[t] = a;
    }
    __syncthreads();

    for (int rr = grp; rr < 64; rr += 8) {
        int l = r0 + rr;
        float qd = Qs[rr * 32 + lane];
        float kd = Ks[rr * 32 + lane];
        float vm = Vs[rr * 32 + lane];
        float s1 = 0.0f;   // (KK q)[d],  d = lane
        float s2 = 0.0f;   // (QQ k)[d]
        float o1 = 0.0f;   // order1[m] = KV[m,:]·q,  m = lane
        #pragma unroll 8
        for (int e = 0; e < 32; ++e) {
            float qe = Qs[rr * 32 + e];   // broadcast; 2 rows/wave -> 2-way (free)
            float ke = Ks[rr * 32 + e];
            s1 += KKs[lane * 33 + e] * qe;
            s2 += QQs[lane * 33 + e] * ke;
            o1 += KVs[lane * 33 + e] * qe;
        }
        float normp = qd * Ksum_s[lane] + 0.5f * qd * s1;
        float kq2p  = kd * s2;
        #pragma unroll
        for (int off = 16; off > 0; off >>= 1) {
            normp += __shfl_xor(normp, off, 32);
            kq2p  += __shfl_xor(kq2p, off, 32);
        }
        out[(l * HH + h) * 32 + lane] = (o1 + 0.5f * kq2p * vm) / normp;
    }
}

extern "C" void kernel_launch(void* const* d_in, const int* in_sizes, int n_in,
                              void* d_out, int out_size, void* d_ws, size_t ws_size,
                              hipStream_t stream) {
    const float* q_in    = (const float*)d_in[0];
    const float* k_in    = (const float*)d_in[1];
    const float* v_in    = (const float*)d_in[2];
    // d_in[3] attn_mask (all ones, unused), d_in[4] query_lengths (unused)
    const float* key_len = (const float*)d_in[5];
    float* ws  = (float*)d_ws;
    float* out = (float*)d_out;

    void* args[] = { &q_in, &k_in, &v_in, &key_len, &ws, &out };
    hipLaunchCooperativeKernel((const void*)fused_kernel, dim3(64), dim3(256),
                               args, 0, stream);
}

// Round 2
// 85.542 us; speedup vs baseline: 1.4101x; 1.4101x over previous
//
#include <hip/hip_runtime.h>
#include <math.h>

#define HH 8
#define LN_EPS 1e-5f
// 1/(3*sqrt(32))
#define KSCALE 0.058925565098878960f

// ws layout (float offsets). Every slot written by K1 before K2 reads it
// (poison-safe: no location is read before being written this launch).
#define KVP_OFF   0        // [64][1024] KV[m][d] partials, block-unique
#define KKP_OFF   65536    // [64][1024] KK[d][e]
#define QQP_OFF   131072   // [64][1024] QQ[d][e]
#define KSUMP_OFF 196608   // [64][32]
#define QN_OFF    198656   // [64][64][32] LN'd Q tile per block
#define KN_OFF    329728   // [64][64][32] LN'd (scaled) K tile per block

// ---------------- Kernel 1: LN + per-block partial reductions ----------------
// grid 64: block b -> head h = b>>3, s-chunk c = b&7 (rows c*64 .. c*64+63).
// No atomics, no memset: partials land in block-unique slots.
__global__ __launch_bounds__(256) void reduce_kernel(
    const float* __restrict__ q_in, const float* __restrict__ k_in,
    const float* __restrict__ v_in, const float* __restrict__ key_len,
    float* __restrict__ ws)
{
    __shared__ float Qs[64 * 32];
    __shared__ float Ks[64 * 32];
    __shared__ float Vs[64 * 32];
    const int b = blockIdx.x, h = b >> 3, c = b & 7, r0 = c * 64;
    const int t = threadIdx.x, lane = t & 31, grp = t >> 5;

    // LayerNorm rows into LDS (each 32-lane group owns 8 rows)
    for (int rr = grp; rr < 64; rr += 8) {
        const int row = r0 + rr;
        const int g = (row * HH + h) * 32 + lane;

        float xq = q_in[g];
        float mq = xq;
        #pragma unroll
        for (int off = 16; off > 0; off >>= 1) mq += __shfl_xor(mq, off, 32);
        mq *= (1.0f / 32.0f);
        float cq = xq - mq;
        float vq = cq * cq;
        #pragma unroll
        for (int off = 16; off > 0; off >>= 1) vq += __shfl_xor(vq, off, 32);
        vq *= (1.0f / 32.0f);
        Qs[rr * 32 + lane] = cq * rsqrtf(vq + LN_EPS);

        float xk = k_in[g];
        float mk = xk;
        #pragma unroll
        for (int off = 16; off > 0; off >>= 1) mk += __shfl_xor(mk, off, 32);
        mk *= (1.0f / 32.0f);
        float ck = xk - mk;
        float vk = ck * ck;
        #pragma unroll
        for (int off = 16; off > 0; off >>= 1) vk += __shfl_xor(vk, off, 32);
        vk *= (1.0f / 32.0f);
        Ks[rr * 32 + lane] = ck * rsqrtf(vk + LN_EPS) * (KSCALE * key_len[row]);

        Vs[rr * 32 + lane] = v_in[g];
    }
    __syncthreads();

    // Export LN'd tiles; the matching finalize block (same b) re-reads them.
    {
        float4* qn4 = (float4*)(ws + QN_OFF) + b * 512;
        float4* kn4 = (float4*)(ws + KN_OFF) + b * 512;
        const float4* qs4 = (const float4*)Qs;
        const float4* ks4 = (const float4*)Ks;
        for (int i = t; i < 512; i += 256) {
            qn4[i] = qs4[i];
            kn4[i] = ks4[i];
        }
    }

    // Partial sums. d = grp*4 + j so the broadcast operand is one ds_read_b128.
    float kv[4] = {0, 0, 0, 0};
    float kk[4] = {0, 0, 0, 0};
    float qq[4] = {0, 0, 0, 0};
    #pragma unroll 4
    for (int s = 0; s < 64; ++s) {
        const float ke = Ks[s * 32 + lane];
        const float ve = Vs[s * 32 + lane];
        const float qe = Qs[s * 32 + lane];
        const float4 kd4 = *(const float4*)&Ks[s * 32 + grp * 4];  // 16B-aligned
        const float4 qd4 = *(const float4*)&Qs[s * 32 + grp * 4];
        kv[0] += kd4.x * ve; kv[1] += kd4.y * ve; kv[2] += kd4.z * ve; kv[3] += kd4.w * ve;
        kk[0] += kd4.x * ke; kk[1] += kd4.y * ke; kk[2] += kd4.z * ke; kk[3] += kd4.w * ke;
        qq[0] += qd4.x * qe; qq[1] += qd4.y * qe; qq[2] += qd4.z * qe; qq[3] += qd4.w * qe;
    }
    #pragma unroll
    for (int j = 0; j < 4; ++j) {
        const int d = grp * 4 + j;
        ws[KVP_OFF + b * 1024 + lane * 32 + d] = kv[j];  // KV[m][d], m = lane
        ws[KKP_OFF + b * 1024 + d * 32 + lane] = kk[j];  // KK[d][e], e = lane
        ws[QQP_OFF + b * 1024 + d * 32 + lane] = qq[j];  // QQ[d][e]
    }
    if (t < 32) {
        float a = 0.0f;
        for (int s = 0; s < 64; ++s) a += Ks[s * 32 + t];  // bank t, conflict-free
        ws[KSUMP_OFF + b * 32 + t] = a;
    }
}

// ---------------- Kernel 2: combine partials + finalize ----------------
// grid 64: block b -> head h = b>>3, l-chunk c = b&7 — same (h,c) map as K1,
// so ws tile b is exactly this block's LN'd Q/K rows.
__global__ __launch_bounds__(256) void finalize_kernel(
    const float* __restrict__ v_in, const float* __restrict__ ws,
    float* __restrict__ out)
{
    // stride-33: row reads T[lane*33+e] hit bank (lane+e)%32 -> conflict-free
    __shared__ float KVs[32 * 33];
    __shared__ float KKs[32 * 33];
    __shared__ float QQs[32 * 33];
    __shared__ float Ksum_s[32];
    __shared__ float Qs[64 * 32];
    __shared__ float Ks[64 * 32];
    const int b = blockIdx.x, h = b >> 3, c = b & 7, r0 = c * 64;
    const int t = threadIdx.x, lane = t & 31, grp = t >> 5;

    // Sum the 8 chunk-partials of head h. Thread t owns floats t*4..t*4+3.
    {
        float4 skv = {0, 0, 0, 0}, skk = {0, 0, 0, 0}, sqq = {0, 0, 0, 0};
        #pragma unroll
        for (int cc = 0; cc < 8; ++cc) {
            const int base = (h * 8 + cc) * 1024 + t * 4;
            const float4 a = *(const float4*)&ws[KVP_OFF + base];
            const float4 d = *(const float4*)&ws[KKP_OFF + base];
            const float4 e = *(const float4*)&ws[QQP_OFF + base];
            skv.x += a.x; skv.y += a.y; skv.z += a.z; skv.w += a.w;
            skk.x += d.x; skk.y += d.y; skk.z += d.z; skk.w += d.w;
            sqq.x += e.x; sqq.y += e.y; sqq.z += e.z; sqq.w += e.w;
        }
        const int r = t >> 3, e0 = (t & 7) * 4;  // bank r+e0+k: 32 distinct per group
        KVs[r * 33 + e0 + 0] = skv.x; KVs[r * 33 + e0 + 1] = skv.y;
        KVs[r * 33 + e0 + 2] = skv.z; KVs[r * 33 + e0 + 3] = skv.w;
        KKs[r * 33 + e0 + 0] = skk.x; KKs[r * 33 + e0 + 1] = skk.y;
        KKs[r * 33 + e0 + 2] = skk.z; KKs[r * 33 + e0 + 3] = skk.w;
        QQs[r * 33 + e0 + 0] = sqq.x; QQs[r * 33 + e0 + 1] = sqq.y;
        QQs[r * 33 + e0 + 2] = sqq.z; QQs[r * 33 + e0 + 3] = sqq.w;
    }
    if (t < 32) {
        float a = 0.0f;
        #pragma unroll
        for (int cc = 0; cc < 8; ++cc) a += ws[KSUMP_OFF + (h * 8 + cc) * 32 + t];
        Ksum_s[t] = a;
    }
    // Reload this block's LN'd tile (written by K1 block b).
    {
        const float4* qn4 = (const float4*)(ws + QN_OFF) + b * 512;
        const float4* kn4 = (const float4*)(ws + KN_OFF) + b * 512;
        float4* qs4 = (float4*)Qs;
        float4* ks4 = (float4*)Ks;
        for (int i = t; i < 512; i += 256) {
            qs4[i] = qn4[i];
            ks4[i] = kn4[i];
        }
    }
    __syncthreads();

    for (int rr = grp; rr < 64; rr += 8) {
        const int l = r0 + rr;
        const int gidx = (l * HH + h) * 32 + lane;
        const float qd = Qs[rr * 32 + lane];
        const float kd = Ks[rr * 32 + lane];
        const float vm = v_in[gidx];
        float s1 = 0.0f;   // (KK q)[d],  d = lane
        float s2 = 0.0f;   // (QQ k)[d]
        float o1 = 0.0f;   // order1[m] = KV[m,:]·q,  m = lane
        #pragma unroll 8
        for (int e = 0; e < 32; ++e) {
            const float qe = Qs[rr * 32 + e];   // 2-way broadcast (free)
            const float ke = Ks[rr * 32 + e];
            s1 += KKs[lane * 33 + e] * qe;
            s2 += QQs[lane * 33 + e] * ke;
            o1 += KVs[lane * 33 + e] * qe;
        }
        float normp = qd * Ksum_s[lane] + 0.5f * qd * s1;
        float kq2p  = kd * s2;
        #pragma unroll
        for (int off = 16; off > 0; off >>= 1) {
            normp += __shfl_xor(normp, off, 32);
            kq2p  += __shfl_xor(kq2p, off, 32);
        }
        out[gidx] = (o1 + 0.5f * kq2p * vm) / normp;
    }
}

extern "C" void kernel_launch(void* const* d_in, const int* in_sizes, int n_in,
                              void* d_out, int out_size, void* d_ws, size_t ws_size,
                              hipStream_t stream) {
    const float* q_in    = (const float*)d_in[0];
    const float* k_in    = (const float*)d_in[1];
    const float* v_in    = (const float*)d_in[2];
    // d_in[3] attn_mask (all ones, unused), d_in[4] query_lengths (unused)
    const float* key_len = (const float*)d_in[5];
    float* ws  = (float*)d_ws;
    float* out = (float*)d_out;

    reduce_kernel<<<64, 256, 0, stream>>>(q_in, k_in, v_in, key_len, ws);
    finalize_kernel<<<64, 256, 0, stream>>>(v_in, ws, out);
}

// Round 3
// 74.491 us; speedup vs baseline: 1.6193x; 1.1484x over previous
//
#include <hip/hip_runtime.h>
#include <math.h>

#define HH 8
#define LN_EPS 1e-5f
// 1/(3*sqrt(32))
#define KSCALE 0.058925565098878960f

// ws float offsets. Block-unique partial slots: no atomics, no memset.
// Every slot is written by K1 before K2 reads it (poison-safe).
#define KVP_OFF   0         // [128][1024]  KV^T partials stored [d][m]
#define KKP_OFF   131072    // [128][1024]  KK[d][e]
#define QQP_OFF   262144    // [128][1024]  QQ[d][e]
#define KSUMP_OFF 393216    // [128][32]

// ---------------- Kernel 1: LN + per-chunk partial reductions ----------------
// grid 128: b = h*16 + c, chunk = rows c*32 .. c*32+31. 256 thr = 8 groups x 32 lanes.
__global__ __launch_bounds__(256) void reduce_kernel(
    const float* __restrict__ q_in, const float* __restrict__ k_in,
    const float* __restrict__ v_in, const float* __restrict__ key_len,
    float* __restrict__ ws)
{
    __shared__ float Qs[32 * 32];
    __shared__ float Ks[32 * 32];
    __shared__ float Vs[32 * 32];
    const int b = blockIdx.x, h = b >> 4, c = b & 15, r0 = c * 32;
    const int t = threadIdx.x, lane = t & 31, grp = t >> 5;

    // ---- LN phase: 4 rows per group; hoist all 12 global loads up-front ----
    float xq[4], xk[4], xv[4], kl[4];
    #pragma unroll
    for (int i = 0; i < 4; ++i) {
        const int rr = grp + i * 8;
        const int g = ((r0 + rr) * HH + h) * 32 + lane;
        xq[i] = q_in[g];
        xk[i] = k_in[g];
        xv[i] = v_in[g];
        kl[i] = key_len[r0 + rr];
    }
    #pragma unroll
    for (int i = 0; i < 4; ++i) {
        const int rr = grp + i * 8;
        float mq = xq[i];
        #pragma unroll
        for (int off = 16; off > 0; off >>= 1) mq += __shfl_xor(mq, off, 32);
        mq *= (1.0f / 32.0f);
        float cq = xq[i] - mq;
        float vq = cq * cq;
        #pragma unroll
        for (int off = 16; off > 0; off >>= 1) vq += __shfl_xor(vq, off, 32);
        vq *= (1.0f / 32.0f);
        Qs[rr * 32 + lane] = cq * rsqrtf(vq + LN_EPS);

        float mk = xk[i];
        #pragma unroll
        for (int off = 16; off > 0; off >>= 1) mk += __shfl_xor(mk, off, 32);
        mk *= (1.0f / 32.0f);
        float ck = xk[i] - mk;
        float vk = ck * ck;
        #pragma unroll
        for (int off = 16; off > 0; off >>= 1) vk += __shfl_xor(vk, off, 32);
        vk *= (1.0f / 32.0f);
        Ks[rr * 32 + lane] = ck * rsqrtf(vk + LN_EPS) * (KSCALE * kl[i]);

        Vs[rr * 32 + lane] = xv[i];
    }
    __syncthreads();

    // ---- Reduce phase: d = grp*4+j, broadcast operand via one ds_read_b128 ----
    float kv[4] = {0, 0, 0, 0};
    float kk[4] = {0, 0, 0, 0};
    float qq[4] = {0, 0, 0, 0};
    float km[4] = {0, 0, 0, 0};
    #pragma unroll 4
    for (int s = 0; s < 32; ++s) {
        const float ke = Ks[s * 32 + lane];
        const float ve = Vs[s * 32 + lane];
        const float qe = Qs[s * 32 + lane];
        const float4 kd4 = *(const float4*)&Ks[s * 32 + grp * 4];  // 16B aligned
        const float4 qd4 = *(const float4*)&Qs[s * 32 + grp * 4];
        kv[0] += kd4.x * ve; kv[1] += kd4.y * ve; kv[2] += kd4.z * ve; kv[3] += kd4.w * ve;
        kk[0] += kd4.x * ke; kk[1] += kd4.y * ke; kk[2] += kd4.z * ke; kk[3] += kd4.w * ke;
        qq[0] += qd4.x * qe; qq[1] += qd4.y * qe; qq[2] += qd4.z * qe; qq[3] += qd4.w * qe;
        km[0] += kd4.x;      km[1] += kd4.y;      km[2] += kd4.z;      km[3] += kd4.w;
    }
    // Stores: [d][*] layout -> per-j wave store covers two 128B segments (coalesced)
    #pragma unroll
    for (int j = 0; j < 4; ++j) {
        const int d = grp * 4 + j;
        ws[KVP_OFF + b * 1024 + d * 32 + lane] = kv[j];  // KV^T[d][m]
        ws[KKP_OFF + b * 1024 + d * 32 + lane] = kk[j];  // KK[d][e]
        ws[QQP_OFF + b * 1024 + d * 32 + lane] = qq[j];  // QQ[d][e]
    }
    if (lane == 0) {
        #pragma unroll
        for (int j = 0; j < 4; ++j) ws[KSUMP_OFF + b * 32 + grp * 4 + j] = km[j];
    }
}

// ---------------- Kernel 2: combine partials + inline LN + finalize ----------------
// grid 512: b = h*64 + lc, rows lc*8 .. lc*8+7 (one 32-lane group per row).
__global__ __launch_bounds__(256) void finalize_kernel(
    const float* __restrict__ q_in, const float* __restrict__ k_in,
    const float* __restrict__ v_in, const float* __restrict__ key_len,
    const float* __restrict__ ws, float* __restrict__ out)
{
    // stride-33: KKs[lane*33+e] banks (lane+e)%32, KVs[e*33+lane] banks (e+lane)%32
    __shared__ float KVs[32 * 33];
    __shared__ float KKs[32 * 33];
    __shared__ float QQs[32 * 33];
    __shared__ float Ksum_s[32];
    __shared__ float qsh[8][32];
    __shared__ float ksh[8][32];
    const int b = blockIdx.x, h = b >> 6, lc = b & 63;
    const int t = threadIdx.x, lane = t & 31, rl = t >> 5;

    // ---- Combine the 16 chunk-partials of head h (48 independent float4 loads) ----
    {
        float4 skv = {0, 0, 0, 0}, skk = {0, 0, 0, 0}, sqq = {0, 0, 0, 0};
        #pragma unroll
        for (int cc = 0; cc < 16; ++cc) {
            const int base = (h * 16 + cc) * 1024 + t * 4;
            const float4 a = *(const float4*)&ws[KVP_OFF + base];
            const float4 d4 = *(const float4*)&ws[KKP_OFF + base];
            const float4 e4 = *(const float4*)&ws[QQP_OFF + base];
            skv.x += a.x;  skv.y += a.y;  skv.z += a.z;  skv.w += a.w;
            skk.x += d4.x; skk.y += d4.y; skk.z += d4.z; skk.w += d4.w;
            sqq.x += e4.x; sqq.y += e4.y; sqq.z += e4.z; sqq.w += e4.w;
        }
        const int r = t >> 3, e0 = (t & 7) * 4;  // element t*4 = row r, col e0
        KVs[r * 33 + e0 + 0] = skv.x; KVs[r * 33 + e0 + 1] = skv.y;
        KVs[r * 33 + e0 + 2] = skv.z; KVs[r * 33 + e0 + 3] = skv.w;
        KKs[r * 33 + e0 + 0] = skk.x; KKs[r * 33 + e0 + 1] = skk.y;
        KKs[r * 33 + e0 + 2] = skk.z; KKs[r * 33 + e0 + 3] = skk.w;
        QQs[r * 33 + e0 + 0] = sqq.x; QQs[r * 33 + e0 + 1] = sqq.y;
        QQs[r * 33 + e0 + 2] = sqq.z; QQs[r * 33 + e0 + 3] = sqq.w;
    }
    if (t < 32) {
        float a = 0.0f;
        #pragma unroll
        for (int cc = 0; cc < 16; ++cc) a += ws[KSUMP_OFF + (h * 16 + cc) * 32 + t];
        Ksum_s[t] = a;
    }

    // ---- Inline LN of this group's own row (no Qn/Kn round-trip) ----
    const int l = lc * 8 + rl;
    const int gidx = (l * HH + h) * 32 + lane;
    const float xq = q_in[gidx];
    const float xk = k_in[gidx];
    const float vm = v_in[gidx];

    float mq = xq;
    #pragma unroll
    for (int off = 16; off > 0; off >>= 1) mq += __shfl_xor(mq, off, 32);
    mq *= (1.0f / 32.0f);
    float cq = xq - mq;
    float vq = cq * cq;
    #pragma unroll
    for (int off = 16; off > 0; off >>= 1) vq += __shfl_xor(vq, off, 32);
    vq *= (1.0f / 32.0f);
    const float qd = cq * rsqrtf(vq + LN_EPS);

    float mk = xk;
    #pragma unroll
    for (int off = 16; off > 0; off >>= 1) mk += __shfl_xor(mk, off, 32);
    mk *= (1.0f / 32.0f);
    float ck = xk - mk;
    float vk = ck * ck;
    #pragma unroll
    for (int off = 16; off > 0; off >>= 1) vk += __shfl_xor(vk, off, 32);
    vk *= (1.0f / 32.0f);
    const float kd = ck * rsqrtf(vk + LN_EPS) * (KSCALE * key_len[l]);

    qsh[rl][lane] = qd;
    ksh[rl][lane] = kd;
    __syncthreads();

    float s1 = 0.0f;   // (KK q)[d],  d = lane
    float s2 = 0.0f;   // (QQ k)[d]
    float o1 = 0.0f;   // order1[m] = sum_d KV^T[d][m] q[d],  m = lane
    #pragma unroll 8
    for (int e = 0; e < 32; ++e) {
        const float qe = qsh[rl][e];   // broadcast (free)
        const float ke = ksh[rl][e];
        s1 += KKs[lane * 33 + e] * qe;
        s2 += QQs[lane * 33 + e] * ke;
        o1 += KVs[e * 33 + lane] * qe;
    }
    float normp = qd * Ksum_s[lane] + 0.5f * qd * s1;
    float kq2p  = kd * s2;
    #pragma unroll
    for (int off = 16; off > 0; off >>= 1) {
        normp += __shfl_xor(normp, off, 32);
        kq2p  += __shfl_xor(kq2p, off, 32);
    }
    out[gidx] = (o1 + 0.5f * kq2p * vm) / normp;
}

extern "C" void kernel_launch(void* const* d_in, const int* in_sizes, int n_in,
                              void* d_out, int out_size, void* d_ws, size_t ws_size,
                              hipStream_t stream) {
    const float* q_in    = (const float*)d_in[0];
    const float* k_in    = (const float*)d_in[1];
    const float* v_in    = (const float*)d_in[2];
    // d_in[3] attn_mask (all ones, unused), d_in[4] query_lengths (unused)
    const float* key_len = (const float*)d_in[5];
    float* ws  = (float*)d_ws;
    float* out = (float*)d_out;

    reduce_kernel<<<128, 256, 0, stream>>>(q_in, k_in, v_in, key_len, ws);
    finalize_kernel<<<512, 256, 0, stream>>>(q_in, k_in, v_in, key_len, ws, out);
}

// Round 4
// 74.383 us; speedup vs baseline: 1.6216x; 1.0015x over previous
//
#include <hip/hip_runtime.h>
#include <math.h>

#define HH 8
#define LN_EPS 1e-5f
// 1/(3*sqrt(32))
#define KSCALE 0.058925565098878960f

// ws float offsets. Block-unique partial slots: no atomics, no memset.
// Every slot is written by K1 before K2 reads it (poison-safe).
#define KVP_OFF   0         // [128][1024]  KV^T partials stored [d][m]
#define KKP_OFF   131072    // [128][1024]  KK[d][e]
#define QQP_OFF   262144    // [128][1024]  QQ[d][e]
#define KSUMP_OFF 393216    // [128][32]

// ---------------- Kernel 1: LN + per-chunk partial reductions ----------------
// grid 128: b = h*16 + c, chunk = rows c*32 .. c*32+31. 256 thr = 8 groups x 32 lanes.
__global__ __launch_bounds__(256) void reduce_kernel(
    const float* __restrict__ q_in, const float* __restrict__ k_in,
    const float* __restrict__ v_in, const float* __restrict__ key_len,
    float* __restrict__ ws)
{
    __shared__ float Qs[32 * 32];
    __shared__ float Ks[32 * 32];
    __shared__ float Vs[32 * 32];
    const int b = blockIdx.x, h = b >> 4, c = b & 15, r0 = c * 32;
    const int t = threadIdx.x, lane = t & 31, grp = t >> 5;

    // ---- LN phase: 4 rows per group; hoist all 12 global loads up-front ----
    float xq[4], xk[4], xv[4], kl[4];
    #pragma unroll
    for (int i = 0; i < 4; ++i) {
        const int rr = grp + i * 8;
        const int g = ((r0 + rr) * HH + h) * 32 + lane;
        xq[i] = q_in[g];
        xk[i] = k_in[g];
        xv[i] = v_in[g];
        kl[i] = key_len[r0 + rr];
    }
    #pragma unroll
    for (int i = 0; i < 4; ++i) {
        const int rr = grp + i * 8;
        float mq = xq[i];
        #pragma unroll
        for (int off = 16; off > 0; off >>= 1) mq += __shfl_xor(mq, off, 32);
        mq *= (1.0f / 32.0f);
        float cq = xq[i] - mq;
        float vq = cq * cq;
        #pragma unroll
        for (int off = 16; off > 0; off >>= 1) vq += __shfl_xor(vq, off, 32);
        vq *= (1.0f / 32.0f);
        Qs[rr * 32 + lane] = cq * rsqrtf(vq + LN_EPS);

        float mk = xk[i];
        #pragma unroll
        for (int off = 16; off > 0; off >>= 1) mk += __shfl_xor(mk, off, 32);
        mk *= (1.0f / 32.0f);
        float ck = xk[i] - mk;
        float vk = ck * ck;
        #pragma unroll
        for (int off = 16; off > 0; off >>= 1) vk += __shfl_xor(vk, off, 32);
        vk *= (1.0f / 32.0f);
        Ks[rr * 32 + lane] = ck * rsqrtf(vk + LN_EPS) * (KSCALE * kl[i]);

        Vs[rr * 32 + lane] = xv[i];
    }
    __syncthreads();

    // ---- Reduce phase: d = grp*4+j, broadcast operand via one ds_read_b128 ----
    float kv[4] = {0, 0, 0, 0};
    float kk[4] = {0, 0, 0, 0};
    float qq[4] = {0, 0, 0, 0};
    float km[4] = {0, 0, 0, 0};
    #pragma unroll 4
    for (int s = 0; s < 32; ++s) {
        const float ke = Ks[s * 32 + lane];
        const float ve = Vs[s * 32 + lane];
        const float qe = Qs[s * 32 + lane];
        const float4 kd4 = *(const float4*)&Ks[s * 32 + grp * 4];  // 16B aligned
        const float4 qd4 = *(const float4*)&Qs[s * 32 + grp * 4];
        kv[0] += kd4.x * ve; kv[1] += kd4.y * ve; kv[2] += kd4.z * ve; kv[3] += kd4.w * ve;
        kk[0] += kd4.x * ke; kk[1] += kd4.y * ke; kk[2] += kd4.z * ke; kk[3] += kd4.w * ke;
        qq[0] += qd4.x * qe; qq[1] += qd4.y * qe; qq[2] += qd4.z * qe; qq[3] += qd4.w * qe;
        km[0] += kd4.x;      km[1] += kd4.y;      km[2] += kd4.z;      km[3] += kd4.w;
    }
    // Stores: [d][*] layout -> per-j wave store covers two 128B segments (coalesced)
    #pragma unroll
    for (int j = 0; j < 4; ++j) {
        const int d = grp * 4 + j;
        ws[KVP_OFF + b * 1024 + d * 32 + lane] = kv[j];  // KV^T[d][m]
        ws[KKP_OFF + b * 1024 + d * 32 + lane] = kk[j];  // KK[d][e]
        ws[QQP_OFF + b * 1024 + d * 32 + lane] = qq[j];  // QQ[d][e]
    }
    if (lane == 0) {
        #pragma unroll
        for (int j = 0; j < 4; ++j) ws[KSUMP_OFF + b * 32 + grp * 4 + j] = km[j];
    }
}

// ---------------- Kernel 2: combine partials + inline LN + finalize ----------------
// grid 256: b = h*32 + lc, rows lc*16 .. lc*16+15 (2 rows per 32-lane group).
// Halved block count vs R3 -> combine redundancy 64x -> 32x per head (50 MB agg).
__global__ __launch_bounds__(256) void finalize_kernel(
    const float* __restrict__ q_in, const float* __restrict__ k_in,
    const float* __restrict__ v_in, const float* __restrict__ key_len,
    const float* __restrict__ ws, float* __restrict__ out)
{
    // stride-33: KKs[lane*33+e] banks (lane+e)%32, KVs[e*33+lane] banks (e+lane)%32
    __shared__ float KVs[32 * 33];
    __shared__ float KKs[32 * 33];
    __shared__ float QQs[32 * 33];
    __shared__ float Ksum_s[32];
    __shared__ float qsh[16][32];
    __shared__ float ksh[16][32];
    const int b = blockIdx.x, h = b >> 5, lc = b & 31;
    const int t = threadIdx.x, lane = t & 31, grp = t >> 5;
    const int l0 = lc * 16 + grp * 2;

    // ---- Hoisted input loads: overlap their latency with the combine below ----
    float xq[2], xk[2], xv[2], kl[2];
    #pragma unroll
    for (int i = 0; i < 2; ++i) {
        const int g = ((l0 + i) * HH + h) * 32 + lane;
        xq[i] = q_in[g];
        xk[i] = k_in[g];
        xv[i] = v_in[g];
        kl[i] = key_len[l0 + i];
    }

    // ---- Combine the 16 chunk-partials of head h (48 independent float4 loads) ----
    {
        float4 skv = {0, 0, 0, 0}, skk = {0, 0, 0, 0}, sqq = {0, 0, 0, 0};
        #pragma unroll
        for (int cc = 0; cc < 16; ++cc) {
            const int base = (h * 16 + cc) * 1024 + t * 4;
            const float4 a  = *(const float4*)&ws[KVP_OFF + base];
            const float4 d4 = *(const float4*)&ws[KKP_OFF + base];
            const float4 e4 = *(const float4*)&ws[QQP_OFF + base];
            skv.x += a.x;  skv.y += a.y;  skv.z += a.z;  skv.w += a.w;
            skk.x += d4.x; skk.y += d4.y; skk.z += d4.z; skk.w += d4.w;
            sqq.x += e4.x; sqq.y += e4.y; sqq.z += e4.z; sqq.w += e4.w;
        }
        const int r = t >> 3, e0 = (t & 7) * 4;  // element t*4 = row r, col e0
        KVs[r * 33 + e0 + 0] = skv.x; KVs[r * 33 + e0 + 1] = skv.y;
        KVs[r * 33 + e0 + 2] = skv.z; KVs[r * 33 + e0 + 3] = skv.w;
        KKs[r * 33 + e0 + 0] = skk.x; KKs[r * 33 + e0 + 1] = skk.y;
        KKs[r * 33 + e0 + 2] = skk.z; KKs[r * 33 + e0 + 3] = skk.w;
        QQs[r * 33 + e0 + 0] = sqq.x; QQs[r * 33 + e0 + 1] = sqq.y;
        QQs[r * 33 + e0 + 2] = sqq.z; QQs[r * 33 + e0 + 3] = sqq.w;
    }
    if (t < 32) {
        float a = 0.0f;
        #pragma unroll
        for (int cc = 0; cc < 16; ++cc) a += ws[KSUMP_OFF + (h * 16 + cc) * 32 + t];
        Ksum_s[t] = a;
    }

    // ---- Inline LN of this group's 2 rows ----
    float qdv[2], kdv[2];
    #pragma unroll
    for (int i = 0; i < 2; ++i) {
        float mq = xq[i];
        #pragma unroll
        for (int off = 16; off > 0; off >>= 1) mq += __shfl_xor(mq, off, 32);
        mq *= (1.0f / 32.0f);
        float cq = xq[i] - mq;
        float vq = cq * cq;
        #pragma unroll
        for (int off = 16; off > 0; off >>= 1) vq += __shfl_xor(vq, off, 32);
        vq *= (1.0f / 32.0f);
        qdv[i] = cq * rsqrtf(vq + LN_EPS);
        qsh[grp * 2 + i][lane] = qdv[i];

        float mk = xk[i];
        #pragma unroll
        for (int off = 16; off > 0; off >>= 1) mk += __shfl_xor(mk, off, 32);
        mk *= (1.0f / 32.0f);
        float ck = xk[i] - mk;
        float vk = ck * ck;
        #pragma unroll
        for (int off = 16; off > 0; off >>= 1) vk += __shfl_xor(vk, off, 32);
        vk *= (1.0f / 32.0f);
        kdv[i] = ck * rsqrtf(vk + LN_EPS) * (KSCALE * kl[i]);
        ksh[grp * 2 + i][lane] = kdv[i];
    }
    __syncthreads();

    // ---- Finalize 2 rows per group ----
    #pragma unroll
    for (int i = 0; i < 2; ++i) {
        const int rr = grp * 2 + i;
        const int gidx = ((l0 + i) * HH + h) * 32 + lane;
        float s1 = 0.0f;   // (KK q)[d],  d = lane
        float s2 = 0.0f;   // (QQ k)[d]
        float o1 = 0.0f;   // order1[m] = sum_d KV^T[d][m] q[d],  m = lane
        #pragma unroll 8
        for (int e = 0; e < 32; ++e) {
            const float qe = qsh[rr][e];   // broadcast / 2-way (free)
            const float ke = ksh[rr][e];
            s1 += KKs[lane * 33 + e] * qe;
            s2 += QQs[lane * 33 + e] * ke;
            o1 += KVs[e * 33 + lane] * qe;
        }
        float normp = qdv[i] * Ksum_s[lane] + 0.5f * qdv[i] * s1;
        float kq2p  = kdv[i] * s2;
        #pragma unroll
        for (int off = 16; off > 0; off >>= 1) {
            normp += __shfl_xor(normp, off, 32);
            kq2p  += __shfl_xor(kq2p, off, 32);
        }
        out[gidx] = (o1 + 0.5f * kq2p * xv[i]) / normp;
    }
}

extern "C" void kernel_launch(void* const* d_in, const int* in_sizes, int n_in,
                              void* d_out, int out_size, void* d_ws, size_t ws_size,
                              hipStream_t stream) {
    const float* q_in    = (const float*)d_in[0];
    const float* k_in    = (const float*)d_in[1];
    const float* v_in    = (const float*)d_in[2];
    // d_in[3] attn_mask (all ones, unused), d_in[4] query_lengths (unused)
    const float* key_len = (const float*)d_in[5];
    float* ws  = (float*)d_ws;
    float* out = (float*)d_out;

    reduce_kernel<<<128, 256, 0, stream>>>(q_in, k_in, v_in, key_len, ws);
    finalize_kernel<<<256, 256, 0, stream>>>(q_in, k_in, v_in, key_len, ws, out);
}